// Round 1
// baseline (53.859 us; speedup 1.0000x reference)
//
#include <hip/hip_runtime.h>

typedef float  f32x4 __attribute__((ext_vector_type(4)));
typedef short  s16x8 __attribute__((ext_vector_type(8)));
typedef unsigned int u32;
typedef unsigned short u16;

#define B_N   8
#define C_N   128
#define HW_N  4096
#define G_N   16
#define K_N   2048
#define O_N   256
#define BM    128
#define BN    128
#define BK    64

__device__ __forceinline__ u16 bf16_bits(float f) {
  u32 u = __builtin_bit_cast(u32, f);
  u32 lsb = (u >> 16) & 1u;
  u += 0x7fffu + lsb;               // round-to-nearest-even
  return (u16)(u >> 16);
}

// ---- prep: W2 f32 [256][2048] -> bf16 row-major in ws ----
__global__ void w2cvt_k(const float* __restrict__ W2, u16* __restrict__ w2b) {
  int i = blockIdx.x * 256 + threadIdx.x;        // 131072 threads x 4 elems
  f32x4 v = reinterpret_cast<const f32x4*>(W2)[i];
  u32 lo = (u32)bf16_bits(v[0]) | ((u32)bf16_bits(v[1]) << 16);
  u32 hi = (u32)bf16_bits(v[2]) | ((u32)bf16_bits(v[3]) << 16);
  u32* dst = reinterpret_cast<u32*>(w2b) + i * 2;
  dst[0] = lo;
  dst[1] = hi;
}

// ---- main fused kernel ----
// out[o, p] = b2[o] + sum_g fm[g,p] * sum_c W2[o, g*128+c] * x[c,p]
// Block: 128 o-rows x 128 pixels. 4 waves (2x2), wave tile 64x64.
__launch_bounds__(256, 2)
__global__ void ccattn_main_k(const float* __restrict__ x,
                              const float* __restrict__ W1,
                              const float* __restrict__ b1,
                              const u16*  __restrict__ w2b,
                              const float* __restrict__ b2,
                              float* __restrict__ out) {
  __shared__ u16   Atile[BM * BK];     // 16 KB, row-major [m][k], XOR-swizzled
  __shared__ u16   xT[BN * C_N];       // 32 KB, [px][c] bf16, XOR-swizzled
  __shared__ float fmT[G_N][BN];       // 8 KB

  const int tid = threadIdx.x;
  const int bid = blockIdx.x;
  const int mt  = bid & 1;             // which half of the 256 output channels
  const int pt  = bid >> 1;            // pixel tile 0..255
  const int b   = pt >> 5;             // batch
  const int px0 = (pt & 31) * BN;

  const float* xb = x + (size_t)b * C_N * HW_N + px0;

  // ---- fused staging: xT (bf16, transposed, swizzled) + fm (f32, exact) ----
  {
    const int px    = tid & 127;
    const int chalf = tid >> 7;        // 0/1 -> channels [0,64) or [64,128)
    const int c0    = chalf * 64;
    float s[8];
#pragma unroll
    for (int gg = 0; gg < 8; ++gg) s[gg] = b1[chalf * 8 + gg];
#pragma unroll
    for (int c = 0; c < 64; c += 2) {
      float v0 = xb[(size_t)(c0 + c) * HW_N + px];
      float v1 = xb[(size_t)(c0 + c + 1) * HW_N + px];
      const int gg = c >> 3;           // group-local (flattened W1 idx = chalf*64 + c)
      s[gg] += v0 * W1[chalf * 64 + c];
      s[gg] += v1 * W1[chalf * 64 + c + 1];
      u32 pk = (u32)bf16_bits(v0) | ((u32)bf16_bits(v1) << 16);
      int byte = (px * 256 + (c0 + c) * 2) ^ ((px & 7) << 4);
      *reinterpret_cast<u32*>(reinterpret_cast<char*>(xT) + byte) = pk;
    }
#pragma unroll
    for (int gg = 0; gg < 8; ++gg) fmT[chalf * 8 + gg][px] = fmaxf(s[gg], 0.0f);
  }
  __syncthreads();

  // ---- wave decomposition ----
  const int w  = tid >> 6;
  const int l  = tid & 63;
  const int wm = w & 1;                // 0/1 -> m offset 0/64
  const int wn = w >> 1;               // 0/1 -> px offset 0/64
  const int lc = l & 15;               // fragment column lane
  const int lk = l >> 4;               // k-group / acc-row group

  f32x4 P[4][4];                       // per-group partial
  f32x4 acc[4][4];                     // scaled accumulator
  const f32x4 zero4 = {0.f, 0.f, 0.f, 0.f};
#pragma unroll
  for (int mf = 0; mf < 4; ++mf)
#pragma unroll
    for (int nf = 0; nf < 4; ++nf) { P[mf][nf] = zero4; acc[mf][nf] = zero4; }

  const u16* w2base = w2b + (size_t)(mt * BM) * K_N;

  // ---- K loop: 32 iters of BK=64; group g = kt>>1 ----
  for (int kt = 0; kt < 32; ++kt) {
    // stage A tile [128 m][64 k] bf16 from w2b (each thread 4 x 16B chunks)
#pragma unroll
    for (int r = 0; r < 4; ++r) {
      int chunk = r * 256 + tid;       // 0..1023
      int m  = chunk >> 3;             // 0..127
      int k8 = chunk & 7;              // 16B chunk within row
      const s16x8 v = *reinterpret_cast<const s16x8*>(
          w2base + (size_t)m * K_N + kt * 64 + k8 * 8);
      int byte = (m * 128 + k8 * 16) ^ ((m & 7) << 4);
      *reinterpret_cast<s16x8*>(reinterpret_cast<char*>(Atile) + byte) = v;
    }
    __syncthreads();

    const int g = kt >> 1;
#pragma unroll
    for (int ks = 0; ks < 2; ++ks) {   // two K=32 MFMA steps
      s16x8 afr[4], bfr[4];
#pragma unroll
      for (int mf = 0; mf < 4; ++mf) {
        int m = wm * 64 + mf * 16 + lc;
        int byte = (m * 128 + (ks * 32 + lk * 8) * 2) ^ ((m & 7) << 4);
        afr[mf] = *reinterpret_cast<const s16x8*>(
            reinterpret_cast<const char*>(Atile) + byte);
      }
#pragma unroll
      for (int nf = 0; nf < 4; ++nf) {
        int px  = wn * 64 + nf * 16 + lc;
        int cch = (kt & 1) * 64 + ks * 32 + lk * 8;   // channel within group
        int byte = (px * 256 + cch * 2) ^ ((px & 7) << 4);
        bfr[nf] = *reinterpret_cast<const s16x8*>(
            reinterpret_cast<const char*>(xT) + byte);
      }
#pragma unroll
      for (int mf = 0; mf < 4; ++mf)
#pragma unroll
        for (int nf = 0; nf < 4; ++nf)
          P[mf][nf] = __builtin_amdgcn_mfma_f32_16x16x32_bf16(
              afr[mf], bfr[nf], P[mf][nf], 0, 0, 0);
    }
    __syncthreads();

    if (kt & 1) {                      // group boundary: acc += fm[g,px] * P
      float s[4];
#pragma unroll
      for (int nf = 0; nf < 4; ++nf) s[nf] = fmT[g][wn * 64 + nf * 16 + lc];
#pragma unroll
      for (int mf = 0; mf < 4; ++mf)
#pragma unroll
        for (int nf = 0; nf < 4; ++nf) {
#pragma unroll
          for (int i = 0; i < 4; ++i) acc[mf][nf][i] += s[nf] * P[mf][nf][i];
          P[mf][nf] = zero4;
        }
    }
  }

  // ---- epilogue: bias + store (f32) ----
  float* outb = out + (size_t)b * O_N * HW_N + px0;
#pragma unroll
  for (int mf = 0; mf < 4; ++mf) {
    int o0 = mt * BM + wm * 64 + mf * 16 + lk * 4;
#pragma unroll
    for (int i = 0; i < 4; ++i) {
      float bias = b2[o0 + i];
#pragma unroll
      for (int nf = 0; nf < 4; ++nf) {
        int px = wn * 64 + nf * 16 + lc;
        outb[(size_t)(o0 + i) * HW_N + px] = acc[mf][nf][i] + bias;
      }
    }
  }
}

extern "C" void kernel_launch(void* const* d_in, const int* in_sizes, int n_in,
                              void* d_out, int out_size, void* d_ws, size_t ws_size,
                              hipStream_t stream) {
  const float* x  = (const float*)d_in[0];
  const float* W1 = (const float*)d_in[1];
  const float* b1 = (const float*)d_in[2];
  const float* W2 = (const float*)d_in[3];
  const float* b2 = (const float*)d_in[4];
  float* out = (float*)d_out;
  u16* w2b = (u16*)d_ws;               // 1 MB bf16 copy of W2

  w2cvt_k<<<512, 256, 0, stream>>>(W2, w2b);
  ccattn_main_k<<<512, 256, 0, stream>>>(x, W1, b1, w2b, b2, out);
}

// Round 2
// 45.505 us; speedup vs baseline: 1.1836x; 1.1836x over previous
//
#include <hip/hip_runtime.h>

typedef float  f32x4 __attribute__((ext_vector_type(4)));
typedef short  s16x8 __attribute__((ext_vector_type(8)));
typedef unsigned int u32;
typedef unsigned short u16;

#define B_N   8
#define C_N   128
#define HW_N  4096
#define G_N   16
#define K_N   2048
#define O_N   256
#define BM    128
#define BN    128

__device__ __forceinline__ u16 bf16_bits(float f) {
  u32 u = __builtin_bit_cast(u32, f);
  u32 lsb = (u >> 16) & 1u;
  u += 0x7fffu + lsb;               // round-to-nearest-even
  return (u16)(u >> 16);
}

// ---- prep: W2 f32 [256][2048] -> bf16 fragment-tiled in ws ----
// layout: byte = (mtile*256 + kc)*256 + (m&15)*16, mtile=m>>4, kc=k>>3.
// i.e. for each (16-row tile, 8-col chunk): 16 lanes x 16B contiguous.
__global__ void w2cvt_k(const float* __restrict__ W2, char* __restrict__ w2t) {
  int t = blockIdx.x * 256 + threadIdx.x;   // 65536 threads
  int w = t >> 6, l = t & 63;
  int mtile = w >> 6;                       // 0..15
  int kc    = (w & 63) * 4 + (l >> 4);      // 0..255
  int m     = mtile * 16 + (l & 15);
  const f32x4* src = reinterpret_cast<const f32x4*>(W2 + (size_t)m * K_N + kc * 8);
  f32x4 v0 = src[0], v1 = src[1];
  s16x8 p;
  p[0]=bf16_bits(v0[0]); p[1]=bf16_bits(v0[1]); p[2]=bf16_bits(v0[2]); p[3]=bf16_bits(v0[3]);
  p[4]=bf16_bits(v1[0]); p[5]=bf16_bits(v1[1]); p[6]=bf16_bits(v1[2]); p[7]=bf16_bits(v1[3]);
  *reinterpret_cast<s16x8*>(w2t + ((size_t)(mtile * 256 + kc) * 256 + (m & 15) * 16)) = p;
}

// ---- main fused kernel ----
// out[o,p] = b2[o] + sum_g fm[g,p] * sum_c W2[o,g*128+c] * x[c,p]
// Block: 128 o x 128 px, 4 waves (2m x 2n), wave tile 64x64.
// B-fragments (xT) cached in regs for ALL groups; A direct from global (L2-hot).
// Main loop has ZERO barriers.
__launch_bounds__(256, 2)
__global__ void ccattn_main_k(const float* __restrict__ x,
                              const float* __restrict__ W1,
                              const float* __restrict__ b1,
                              const char* __restrict__ w2t,
                              const float* __restrict__ b2,
                              float* __restrict__ out) {
  __shared__ u16   xT[BN * C_N];       // 32 KB, [px][c] bf16, XOR-swizzled
  __shared__ float fmT[G_N][BN];       // 8 KB

  const int tid = threadIdx.x;
  const int bid = blockIdx.x;
  const int mt  = bid & 1;             // output-channel half
  const int pt  = bid >> 1;
  const int b   = pt >> 5;
  const int px0 = (pt & 31) * BN;

  const float* xb = x + (size_t)b * C_N * HW_N + px0;

  // ---- staging: xT (bf16, [px][c], swizzled, b128 writes) + fm ----
  {
    const int px    = tid & 127;
    const int chalf = tid >> 7;        // channels [0,64) or [64,128)
#pragma unroll
    for (int gg = 0; gg < 8; ++gg) {
      const int g  = chalf * 8 + gg;
      const int c0 = g * 8;
      float v[8];
#pragma unroll
      for (int j = 0; j < 8; ++j) v[j] = xb[(size_t)(c0 + j) * HW_N + px];
      float s = b1[g];
#pragma unroll
      for (int j = 0; j < 8; ++j) s += v[j] * W1[g * 8 + j];
      fmT[g][px] = fmaxf(s, 0.0f);
      s16x8 p;
#pragma unroll
      for (int j = 0; j < 8; ++j) p[j] = (short)bf16_bits(v[j]);
      int byte = (px * 256 + c0 * 2) ^ ((px & 15) << 4);
      *reinterpret_cast<s16x8*>(reinterpret_cast<char*>(xT) + byte) = p;
    }
  }
  __syncthreads();

  // ---- wave decomposition ----
  const int w  = tid >> 6;
  const int l  = tid & 63;
  const int wm = w & 1;
  const int wn = w >> 1;
  const int lc = l & 15;
  const int lk = l >> 4;

  // ---- B-fragment register cache: [ks][nf], valid for every group ----
  s16x8 bfr[4][4];
#pragma unroll
  for (int ks = 0; ks < 4; ++ks)
#pragma unroll
    for (int nf = 0; nf < 4; ++nf) {
      int px  = wn * 64 + nf * 16 + lc;
      int byte = (px * 256 + (ks * 32 + lk * 8) * 2) ^ ((px & 15) << 4);
      bfr[ks][nf] = *reinterpret_cast<const s16x8*>(
          reinterpret_cast<const char*>(xT) + byte);
    }

  f32x4 acc[4][4];
  const f32x4 Z = {0.f, 0.f, 0.f, 0.f};
#pragma unroll
  for (int mf = 0; mf < 4; ++mf)
#pragma unroll
    for (int nf = 0; nf < 4; ++nf) acc[mf][nf] = Z;

  // per-mf A base: w2t byte = mtile*65536 + g*4096 + ks*1024 + lk*256 + lc*16
  const char* abase[4];
#pragma unroll
  for (int mf = 0; mf < 4; ++mf)
    abase[mf] = w2t + (size_t)(mt * 8 + wm * 4 + mf) * 65536 + lk * 256 + lc * 16;

  // ---- main loop over 16 groups, no barriers ----
  for (int g = 0; g < 16; ++g) {
    float sn[4];
#pragma unroll
    for (int nf = 0; nf < 4; ++nf) sn[nf] = fmT[g][wn * 64 + nf * 16 + lc];

    f32x4 P[4][4];
#pragma unroll
    for (int ks = 0; ks < 4; ++ks) {
      s16x8 afr[4];
#pragma unroll
      for (int mf = 0; mf < 4; ++mf)
        afr[mf] = *reinterpret_cast<const s16x8*>(abase[mf] + g * 4096 + ks * 1024);
#pragma unroll
      for (int mf = 0; mf < 4; ++mf)
#pragma unroll
        for (int nf = 0; nf < 4; ++nf)
          P[mf][nf] = __builtin_amdgcn_mfma_f32_16x16x32_bf16(
              afr[mf], bfr[ks][nf], ks == 0 ? Z : P[mf][nf], 0, 0, 0);
    }
#pragma unroll
    for (int mf = 0; mf < 4; ++mf)
#pragma unroll
      for (int nf = 0; nf < 4; ++nf)
#pragma unroll
        for (int i = 0; i < 4; ++i)
          acc[mf][nf][i] += sn[nf] * P[mf][nf][i];
  }

  // ---- epilogue: bias + store ----
  float* outb = out + (size_t)b * O_N * HW_N + px0;
#pragma unroll
  for (int mf = 0; mf < 4; ++mf) {
    int o0 = mt * BM + wm * 64 + mf * 16 + lk * 4;
#pragma unroll
    for (int i = 0; i < 4; ++i) {
      float bias = b2[o0 + i];
#pragma unroll
      for (int nf = 0; nf < 4; ++nf) {
        int px = wn * 64 + nf * 16 + lc;
        outb[(size_t)(o0 + i) * HW_N + px] = acc[mf][nf][i] + bias;
      }
    }
  }
}

extern "C" void kernel_launch(void* const* d_in, const int* in_sizes, int n_in,
                              void* d_out, int out_size, void* d_ws, size_t ws_size,
                              hipStream_t stream) {
  const float* x  = (const float*)d_in[0];
  const float* W1 = (const float*)d_in[1];
  const float* b1 = (const float*)d_in[2];
  const float* W2 = (const float*)d_in[3];
  const float* b2 = (const float*)d_in[4];
  float* out = (float*)d_out;
  char* w2t = (char*)d_ws;             // 1 MB tiled bf16 copy of W2

  w2cvt_k<<<256, 256, 0, stream>>>(W2, w2t);
  ccattn_main_k<<<512, 256, 0, stream>>>(x, W1, b1, w2t, b2, out);
}